// Round 8
// baseline (286.467 us; speedup 1.0000x reference)
//
#include <hip/hip_runtime.h>

// ---------------------------------------------------------------------------
// HolographicMemory: out = softmax( x @ [Kr|Ki]^T * temp ) @ [Vr|Vi]
// v9: OCCUPANCY DOUBLING. Measured invariant across v5-v8 and m97: per-wave
//     progress is ~190 wall-cyc/MFMA; throughput = rate x resident waves.
//     v8 was register-capped (128 VGPR + 128 AGPR acc) at 2 waves/SIMD.
//     v9 halves the wave tile (64x64, acc[4][4] = 64 regs) -> <=128 unified
//     regs -> 4 waves/SIMD (16/CU). Same verified v7/v8 period structure,
//     fragment layouts, swizzles; 512-thr blocks (8 waves), grid 512.
// ---------------------------------------------------------------------------

#define DIMX   1024
#define MEMN   512
#define NROWS  32768
#define TEMP   0.04419417382415922f  // 512^-0.5

typedef __bf16 bf16;
typedef __bf16 bf16x8 __attribute__((ext_vector_type(8)));
typedef float  f32x4  __attribute__((ext_vector_type(4)));

__device__ __forceinline__ void gl_b16x8(bf16x8& d, const bf16* p) {
    asm volatile("global_load_dwordx4 %0, %1, off" : "=v"(d) : "v"(p));
}
__device__ __forceinline__ void gl_f32x4(f32x4& d, const float* p) {
    asm volatile("global_load_dwordx4 %0, %1, off" : "=v"(d) : "v"(p));
}
#define VMW(N)     do { asm volatile("s_waitcnt vmcnt(" #N ")" ::: "memory"); \
                        __builtin_amdgcn_sched_barrier(0); } while (0)
#define WAITBAR(N) do { asm volatile("s_waitcnt vmcnt(" #N ") lgkmcnt(0)\n\t" \
                        "s_barrier" ::: "memory");                            \
                        __builtin_amdgcn_sched_barrier(0); } while (0)

// ---- pack K' and V'^T in MFMA-fragment order (verified r3-r7) -------------
// Kb_f[c][t][l][e]: element (row=t*16+lm, k=c*32+g*8+e) of K'=[Kr|Ki]
// Vb_f[c][t][l][e]: element (h=t*16+lm, mem=c*32+g*8+e) of V'^T [1024][512]
__global__ __launch_bounds__(256) void pack_kv_kernel(const float* __restrict__ kr,
                                                      const float* __restrict__ ki,
                                                      const float* __restrict__ vr,
                                                      const float* __restrict__ vi,
                                                      bf16* __restrict__ Kb,
                                                      bf16* __restrict__ Vb) {
    const int idx = blockIdx.x * 256 + threadIdx.x;   // 0 .. 2^19-1
    const int e = idx & 7, l = (idx >> 3) & 63;
    const int lm = l & 15, g = l >> 4;
    {   // Kb_f
        const int t = (idx >> 9) & 31, c = idx >> 14;
        const int row = t * 16 + lm, k = c * 32 + g * 8 + e;
        const float v = (k < 512) ? kr[row * 512 + k] : ki[row * 512 + (k - 512)];
        Kb[idx] = (bf16)v;
    }
    {   // Vb_f
        const int t = (idx >> 9) & 63, c = idx >> 15;
        const int h = t * 16 + lm, m = c * 32 + g * 8 + e;
        const float v = (h < 512) ? vr[m * 512 + h] : vi[m * 512 + (h - 512)];
        Vb[idx] = (bf16)v;
    }
}

// ---------------------------------------------------------------------------
// Fused kernel. Block = 64 x-rows, 512 thr (8 waves), grid 512 (2 blocks/CU,
// 16 waves/CU with __launch_bounds__(512,4)).
// Energy: wave wv owns cols wv*64..+63 -> acc[4][4]; K frag-direct from L2
//   (4 loads/period, double-buffered regs); X reg->LDS (2x8KB, swizzled).
// Softmax: per-wave partials + 8-wave LDS combine.
// P[64][512] bf16 -> LDS (chunk-XOR swizzle). PV: wave owns out cols
//   wv*128..+127 (2 halves, acc reuse), V frag-direct from L2.
// ---------------------------------------------------------------------------
__global__ __launch_bounds__(512, 4) void fused_kernel(
        const float* __restrict__ x,    // [32768][1024] fp32
        const bf16*  __restrict__ Kb,   // fragment-order, 1 MiB
        const bf16*  __restrict__ Vb,   // fragment-order, 1 MiB
        float* __restrict__ out) {      // [32768][1024] fp32
    __shared__ __align__(16) char smem[65536];
    // overlay: energy: [0,16384) Xs[2][64*64bf16], [16384,20480) red[64][8][2]
    //          PV:     [0,65536) P[64][512] bf16 (chunk-swizzled)
    float (*red)[8][2] = (float (*)[8][2])(smem + 16384);
    char* Pl = smem;

    const int tid  = threadIdx.x;
    const int wv   = tid >> 6, lane = tid & 63;
    const int lm   = lane & 15, g = lane >> 4;
    const int rowB = blockIdx.x * 64;

    // X staging: thread -> row sr (0..63), 8-fp32 slice sc (0..7)
    const int sr = tid >> 3, sc = tid & 7;
    const float* xsrc = x + (size_t)(rowB + sr) * DIMX + sc * 8;

    const bf16* kbase = Kb + (wv * 4) * 512 + lane * 8;

    f32x4 acc[4][4] = {};
    f32x4 xa0, xa1;
    bf16x8 kfA[4], kfB[4];

#define K_PREF(DST, C) { _Pragma("unroll") for (int j = 0; j < 4; ++j)         \
        gl_b16x8(DST[j], kbase + (size_t)(C) * 16384 + j * 512); }
#define X_PREF(P) { gl_f32x4(xa0, xsrc + (P) * 64);                            \
                    gl_f32x4(xa1, xsrc + (P) * 64 + 4); }
#define X_WR(B) { bf16x8 w;                                                    \
    w[0]=(bf16)xa0[0]; w[1]=(bf16)xa0[1]; w[2]=(bf16)xa0[2]; w[3]=(bf16)xa0[3]; \
    w[4]=(bf16)xa1[0]; w[5]=(bf16)xa1[1]; w[6]=(bf16)xa1[2]; w[7]=(bf16)xa1[3]; \
    *(bf16x8*)(smem + (B) * 8192 + sr * 128 + ((sc ^ (sr & 7)) << 4)) = w; }
#define COMPUTE_E(PB, S, KF) { bf16x8 af[4];                                   \
    _Pragma("unroll") for (int i = 0; i < 4; ++i) { const int r = i * 16 + lm; \
        af[i] = *(const bf16x8*)(smem + (PB) * 8192 + r * 128                  \
                                 + (((((S) * 4) + g) ^ (r & 7)) << 4)); }      \
    __builtin_amdgcn_s_setprio(1);                                             \
    _Pragma("unroll") for (int i = 0; i < 4; ++i)                              \
        _Pragma("unroll") for (int j = 0; j < 4; ++j)                          \
            acc[i][j] = __builtin_amdgcn_mfma_f32_16x16x32_bf16(               \
                af[i], KF[j], acc[i][j], 0, 0, 0);                             \
    __builtin_amdgcn_s_setprio(0); }

    // ---- energy prologue ----------------------------------------------------
    X_PREF(0);                 // 2
    K_PREF(kfA, 0);            // +4 -> 6
    VMW(4);                    // retire X(0)
    X_WR(0);
    X_PREF(1);                 // -> 6
    WAITBAR(6);                // barrier-only; publish Xs[0]

    // ---- energy periods 0..13 (BK=64, one barrier per period) ---------------
    // entry queue: [K(2p):4, X(p+1):2] = 6
    for (int p = 0; p < 14; ++p) {
        const int pb = p & 1;
        K_PREF(kfB, 2 * p + 1);    // -> 10
        VMW(6);                    // retire K(2p)   [full-period coverage]
        COMPUTE_E(pb, 0, kfA);
        K_PREF(kfA, 2 * p + 2);    // -> 10
        VMW(4);                    // retire X(p+1) + K(2p+1)
        COMPUTE_E(pb, 1, kfB);
        X_WR(pb ^ 1);
        X_PREF(p + 2);             // -> 6
        WAITBAR(6);                // barrier-only
    }
    // ---- period 14 (pb=0) ---------------------------------------------------
    K_PREF(kfB, 29);           // -> 10
    VMW(6);                    // retire K(28)
    COMPUTE_E(0, 0, kfA);
    K_PREF(kfA, 30);           // -> 10
    VMW(4);                    // retire X(15) + K(29)
    COMPUTE_E(0, 1, kfB);
    X_WR(1);
    WAITBAR(4);                // leaves K(30):4
    // ---- period 15 (pb=1) ---------------------------------------------------
    K_PREF(kfB, 31);           // -> 8
    VMW(4);                    // retire K(30)
    COMPUTE_E(1, 0, kfA);
    VMW(0);                    // retire K(31)
    COMPUTE_E(1, 1, kfB);

#undef K_PREF
#undef X_PREF
#undef X_WR
#undef COMPUTE_E

    // ---- softmax ------------------------------------------------------------
    // C/D layout: col = j*16 + lm (+wv*64), row = i*16 + g*4 + reg.
    float fac[4][4];
    #pragma unroll
    for (int i = 0; i < 4; ++i) {
        #pragma unroll
        for (int rg = 0; rg < 4; ++rg) {
            float m = acc[i][0][rg] * TEMP;
            #pragma unroll
            for (int j = 1; j < 4; ++j) m = fmaxf(m, acc[i][j][rg] * TEMP);
            m = fmaxf(m, __shfl_xor(m, 1));
            m = fmaxf(m, __shfl_xor(m, 2));
            m = fmaxf(m, __shfl_xor(m, 4));
            m = fmaxf(m, __shfl_xor(m, 8));
            float s = 0.f;
            #pragma unroll
            for (int j = 0; j < 4; ++j) {
                const float v = __expf(acc[i][j][rg] * TEMP - m);
                acc[i][j][rg] = v;
                s += v;
            }
            s += __shfl_xor(s, 1);
            s += __shfl_xor(s, 2);
            s += __shfl_xor(s, 4);
            s += __shfl_xor(s, 8);
            const int rr = i * 16 + g * 4 + rg;
            if (lm == 0) { red[rr][wv][0] = m; red[rr][wv][1] = s; }
            fac[i][rg] = m;
        }
    }
    __syncthreads();           // red published
    #pragma unroll
    for (int i = 0; i < 4; ++i) {
        #pragma unroll
        for (int rg = 0; rg < 4; ++rg) {
            const int rr = i * 16 + g * 4 + rg;
            float M = red[rr][0][0];
            #pragma unroll
            for (int w = 1; w < 8; ++w) M = fmaxf(M, red[rr][w][0]);
            float S = 0.f;
            #pragma unroll
            for (int w = 0; w < 8; ++w)
                S += red[rr][w][1] * __expf(red[rr][w][0] - M);
            fac[i][rg] = __expf(fac[i][rg] - M) / S;
        }
    }
    __syncthreads();           // red reads done -> safe to overwrite with P

    // ---- scatter P -> LDS (chunk-XOR swizzle) -------------------------------
    // P byte addr: row*1024 + (((col>>3) ^ (row&7))<<4) + (col&7)*2
    {
        const int cb = wv * 8 + (lm >> 3);    // col>>3 = cb + j*2
        const int ce = (lm & 7) * 2;
        #pragma unroll
        for (int i = 0; i < 4; ++i) {
            #pragma unroll
            for (int rg = 0; rg < 4; ++rg) {
                const int row = i * 16 + g * 4 + rg;
                const int rx  = row & 7;
                const float f = fac[i][rg];
                char* prow = Pl + row * 1024 + ce;
                #pragma unroll
                for (int j = 0; j < 4; ++j)
                    *(bf16*)(prow + (((cb + j * 2) ^ rx) << 4))
                        = (bf16)(acc[i][j][rg] * f);
            }
        }
    }
    __syncthreads();           // P visible to all waves

    // ---- PV: out[64][1024] = P @ V', wave owns cols wv*128..+127 ------------
#define PV_COMPUTE(BF, KS) { bf16x8 af[4];                                     \
    _Pragma("unroll") for (int i = 0; i < 4; ++i) { const int r = i * 16 + lm; \
        af[i] = *(const bf16x8*)(Pl + r * 1024                                 \
                                 + ((((KS) * 4 + g) ^ (r & 7)) << 4)); }       \
    __builtin_amdgcn_s_setprio(1);                                             \
    _Pragma("unroll") for (int i = 0; i < 4; ++i)                              \
        _Pragma("unroll") for (int j = 0; j < 4; ++j)                          \
            acc[i][j] = __builtin_amdgcn_mfma_f32_16x16x32_bf16(               \
                af[i], BF[j], acc[i][j], 0, 0, 0);                             \
    __builtin_amdgcn_s_setprio(0); }
#define V_PREF(DST, KS) { _Pragma("unroll") for (int j = 0; j < 4; ++j)        \
        gl_b16x8(DST[j], vb + (size_t)(KS) * 32768 + j * 512); }

    #pragma unroll
    for (int h = 0; h < 2; ++h) {
        #pragma unroll
        for (int i = 0; i < 4; ++i)
            #pragma unroll
            for (int j = 0; j < 4; ++j)
                acc[i][j] = (f32x4){0.f, 0.f, 0.f, 0.f};

        const bf16* vb = Vb + (size_t)(wv * 8 + h * 4) * 512 + lane * 8;
        bf16x8 bv0[4], bv1[4];
        V_PREF(bv0, 0);
        for (int ks = 0; ks < 14; ks += 2) {
            V_PREF(bv1, ks + 1); VMW(4); PV_COMPUTE(bv0, ks);
            V_PREF(bv0, ks + 2); VMW(4); PV_COMPUTE(bv1, ks + 1);
        }
        V_PREF(bv1, 15); VMW(4); PV_COMPUTE(bv0, 14);
        VMW(0);          PV_COMPUTE(bv1, 15);

        // store half: rows rowB+i*16+g*4+rg, cols wv*128 + h*64 + j*16 + lm
        const int c0 = wv * 128 + h * 64 + lm;
        #pragma unroll
        for (int i = 0; i < 4; ++i) {
            #pragma unroll
            for (int j = 0; j < 4; ++j) {
                #pragma unroll
                for (int rg = 0; rg < 4; ++rg)
                    out[(size_t)(rowB + i * 16 + g * 4 + rg) * DIMX
                        + (c0 + j * 16)] = acc[i][j][rg];
            }
        }
    }

#undef PV_COMPUTE
#undef V_PREF
}

// ---------------------------------------------------------------------------
extern "C" void kernel_launch(void* const* d_in, const int* in_sizes, int n_in,
                              void* d_out, int out_size, void* d_ws, size_t ws_size,
                              hipStream_t stream) {
    const float* x  = (const float*)d_in[0];
    const float* kr = (const float*)d_in[1];
    const float* ki = (const float*)d_in[2];
    const float* vr = (const float*)d_in[3];
    const float* vi = (const float*)d_in[4];
    float* out = (float*)d_out;

    char* ws = (char*)d_ws;
    bf16* Kb = (bf16*)ws;                  // 1 MiB (fragment order)
    bf16* Vb = (bf16*)(ws + 1048576);      // 1 MiB (fragment order)

    pack_kv_kernel<<<2048, 256, 0, stream>>>(kr, ki, vr, vi, Kb, Vb);
    fused_kernel<<<512, 512, 0, stream>>>(x, Kb, Vb, out);
}